// Round 9
// baseline (23.681 us; speedup 1.0000x reference)
//
#include <hip/hip_runtime.h>
#include <math.h>

#define NVOICE 8
#define NPROF  16
#define NHARM  64
#define NFRAME 64
#define NSAMP  16384
#define NB     16

// Only harmonics h in [0,15] can ever have freq < 1.0.  For h >= 16,
// base*(h+1)^2 >= MIN_FREQ*289 = 1.048 > 1 for every frame, so freq clips
// to exactly 1.0, the phase prefix is an even integer, S is an integer,
// and sin(pi*S) == 0 exactly: those rows contribute nothing.
#define NKEEP  16
#define NROWS2 (NVOICE * NKEEP)        // 128 rows per batch

// MIN_FREQ = FREQ_INTERVAL = 40 / 11025
__device__ __forceinline__ float min_freq() { return 40.0f / 11025.0f; }

// ---------------------------------------------------------------------------
// Kernel 1: record builder.  Block = (batch, octet of 8 chunks).  Computes
// base/amp0 (all frames), the f64 phase prefix (serial over <= c_hi frames,
// 128 rows in parallel), softmax+amps at the 10 frames this octet touches,
// then writes per-(chunk,half) row records to ws:
//   rec4[((b*64+c)*2+h)*128 + r] = {F2, dF2, A, dA}     (float4, 4 MB)
//   recP[((b*64+c)*2+h)*128 + r] = P2                   (float,  1 MB)
// where F2 = F/2, P2 = (phase-prefix/2) mod 1 (f64-exact), half h: sample
// segment fA = c-1+h (clamped), fB = fA+1.
// ---------------------------------------------------------------------------
__global__ __launch_bounds__(256)
void hm_recs(const float* __restrict__ f0,
             const float* __restrict__ harm,
             const float* __restrict__ prof,
             float4* __restrict__ rec4,
             float* __restrict__ recP)
{
    const int blk  = blockIdx.x;         // 0..127
    const int b    = blk >> 3;
    const int o    = blk & 7;            // chunk octet: chunks 8o .. 8o+7
    const int c_lo = 8 * o;
    const int c_hi = c_lo + 7;
    const int tid  = threadIdx.x;        // 0..255

    __shared__ float sBase[NVOICE][NFRAME];
    __shared__ float sAmp0[NVOICE][NFRAME];
    __shared__ float sProf[NPROF][NKEEP];
    __shared__ float sW[NVOICE][10][NPROF];  // softmax at the 10 frames
    __shared__ float sPP[9][NROWS2];         // P2 at frames c_lo-1 .. c_hi
    __shared__ float sA[10][NROWS2];         // amps at frames c_lo-1 .. c_hi+1

    // ---- step 1: prof; base & amp0 for all (v, k) -------------------------
    sProf[tid >> 4][tid & 15] = prof[(tid >> 4) * NHARM + (tid & 15)];

    for (int idx = tid; idx < NVOICE * NFRAME; idx += 256) {
        const int v = idx >> 6, k = idx & 63;
        const float re  = f0[((size_t)b * 16 + 2 * v    ) * NFRAME + k];
        const float im  = f0[((size_t)b * 16 + 2 * v + 1) * NFRAME + k];
        const float ang = atan2f(im, re) * 0.3183098861837907f;   // /pi
        sBase[v][k] = min_freq() + ang * ang * min_freq();
        sAmp0[v][k] = re * re + im * im;
    }
    if (c_lo == 0 && tid < NROWS2) sPP[0][tid] = 0.0f;   // frame -1 prefix
    __syncthreads();

    // ---- step 2: phase prefix (threads 0-127) || softmax (128-207) --------
    if (tid < NROWS2) {
        // row r = v*16 + h; term_0 = 64*F_0; term_k = 64*(F_{k-1}+F_k);
        // P2_k = frac(sum) in f64 (exact enough: |sum| <= 16384).
        const int r = tid, v = r >> 4, hh = r & 15;
        const float r2 = (float)((hh + 1) * (hh + 1));
        double p = 0.0;
        float prevF = 0.0f;
        for (int k = 0; k <= c_hi; ++k) {
            const float F = fminf(sBase[v][k] * r2, 1.0f);
            p += 64.0 * (double)(prevF + F);     // k==0: 64*F_0
            prevF = F;
            const int fi = k - (c_lo - 1);
            if (fi >= 0) sPP[fi][r] = (float)(p - floor(p));   // fi <= 8
        }
    } else if (tid < 128 + 80) {
        // 80 softmaxes: (v, fi) over the 10 frames c_lo-1 .. c_hi+1 (clamped)
        const int t = tid - 128;
        const int v = t / 10, fi = t % 10;
        const int f = min(max(c_lo - 1 + fi, 0), 63);
        float w[NPROF];
        float m = -INFINITY;
#pragma unroll
        for (int p = 0; p < NPROF; ++p) {
            w[p] = harm[((size_t)b * (NVOICE * NPROF) + v * NPROF + p) * NFRAME + f];
            m = fmaxf(m, w[p]);
        }
        float s = 0.0f;
#pragma unroll
        for (int p = 0; p < NPROF; ++p) { w[p] = expf(w[p] - m); s += w[p]; }
        const float inv = 1.0f / s;
#pragma unroll
        for (int p = 0; p < NPROF; ++p) sW[v][fi][p] = w[p] * inv;
    }
    __syncthreads();

    // ---- step 3: amplitudes at the 10 frames (1280 values) ----------------
    for (int idx = tid; idx < 10 * NROWS2; idx += 256) {
        const int fi = idx >> 7, r = idx & 127, v = r >> 4, hh = r & 15;
        const int f = min(max(c_lo - 1 + fi, 0), 63);
        const float a0 = sAmp0[v][f];
        float A = a0;                            // hh==0: fundamental
        if (hh != 0) {
            float d = 0.0f;
#pragma unroll
            for (int p = 0; p < NPROF; ++p) d = fmaf(sW[v][fi][p], sProf[p][hh - 1], d);
            A = fminf(fmaxf(d, 0.0f), 1.0f) * a0;
        }
        sA[fi][r] = A;
    }
    __syncthreads();

    // ---- step 4: emit records (8 chunks x 2 halves x 128 rows) ------------
    for (int idx = tid; idx < 16 * NROWS2; idx += 256) {
        const int crel = idx >> 8;               // chunk within octet
        const int rest = idx & 255;
        const int hh   = rest >> 7;              // segment half
        const int r    = rest & 127;
        const int v    = r >> 4, hr = r & 15;
        const float r2 = (float)((hr + 1) * (hr + 1));
        const int c  = c_lo + crel;
        const int fA = min(max(c - 1 + hh, 0), 63);
        const int fB = min(c + hh, 63);
        const float Fa = 0.5f * fminf(sBase[v][fA] * r2, 1.0f);
        const float Fb = 0.5f * fminf(sBase[v][fB] * r2, 1.0f);
        const int fiA = crel + hh, fiB = fiA + 1;   // sA index (clamp inside)
        const float Aa = sA[fiA][r], Ab = sA[fiB][r];
        const size_t oidx = ((((size_t)b * 64 + c) * 2 + hh) * NROWS2) + r;
        rec4[oidx] = make_float4(Fa, Fb - Fa, Aa, Ab - Aa);
        recP[oidx] = (c == 0 && hh == 0) ? 0.0f : sPP[crel + hh][r];
    }
}

// ---------------------------------------------------------------------------
// Kernel 2: streaming synthesis.  Block = one wave = one (batch, chunk,
// half): 64 lanes x 2 samples.  No LDS, no barriers; record reads are
// wave-uniform (coalesce to one transaction / scalarize to s_load).
//   samples s = h*128 + l + {0,64}; in-segment j = s + (h ? -128 : +128)
//   S/2 = P2 + t1*F2 + t2*dF2,  t1=j+1, t2=(j+1)^2/512,  fa = A + t3*dA
//   sin(pi*S) = v_sin_f32(fract(S/2))   [v_sin takes revolutions]
// Head (c==0,h==0): records already have P=0, dF=0; override t1 = s+1.
// Tail (c==63,h==1): t1=j+1 is already correct, dF=dA=0 from clamped fB.
// ---------------------------------------------------------------------------
__global__ __launch_bounds__(64)
void hm_synth(const float4* __restrict__ rec4,
              const float* __restrict__ recP,
              float* __restrict__ out)
{
    const int blk  = blockIdx.x;         // 0..2047
    const int b    = blk >> 7;
    const int rest = blk & 127;
    const int c    = rest >> 1;
    const int h    = rest & 1;
    const int l    = threadIdx.x;        // 0..63

    const int j0 = l + (h ? 0 : 128);    // in-segment index for sample 0
    const int j1 = j0 + 64;

    float t1a = (float)(j0 + 1);
    float t1b = (float)(j1 + 1);
    if (c == 0 && h == 0) {              // flat head: S = (s+1)*F0
        t1a = (float)(l + 1);
        t1b = (float)(l + 65);
    }
    const float t2a = (float)((j0 + 1) * (j0 + 1)) * (1.0f / 512.0f);
    const float t2b = (float)((j1 + 1) * (j1 + 1)) * (1.0f / 512.0f);
    const float t3a = ((float)j0 + 0.5f) * (1.0f / 256.0f);
    const float t3b = ((float)j1 + 0.5f) * (1.0f / 256.0f);

    const size_t base = (((size_t)b * 64 + c) * 2 + h) * NROWS2;
    const float4* __restrict__ V = rec4 + base;
    const float*  __restrict__ P = recP + base;

    float acc0 = 0.0f, acc1 = 0.0f;
#pragma unroll 8
    for (int r = 0; r < NROWS2; ++r) {
        const float4 vv = V[r];
        const float  pp = P[r];
        const float x0 = fmaf(t2a, vv.y, fmaf(t1a, vv.x, pp));
        const float x1 = fmaf(t2b, vv.y, fmaf(t1b, vv.x, pp));
        const float fa0 = fmaf(t3a, vv.w, vv.z);
        const float fa1 = fmaf(t3b, vv.w, vv.z);
        acc0 = fmaf(fa0, __builtin_amdgcn_sinf(__builtin_amdgcn_fractf(x0)), acc0);
        acc1 = fmaf(fa1, __builtin_amdgcn_sinf(__builtin_amdgcn_fractf(x1)), acc1);
    }

    float* o = out + (size_t)b * NSAMP + c * 256 + h * 128 + l;
    o[0]  = acc0;
    o[64] = acc1;
}

// ---------------------------------------------------------------------------
extern "C" void kernel_launch(void* const* d_in, const int* in_sizes, int n_in,
                              void* d_out, int out_size, void* d_ws, size_t ws_size,
                              hipStream_t stream)
{
    const float* f0   = (const float*)d_in[0];   // (16, 16, 64)
    const float* harm = (const float*)d_in[1];   // (16, 128, 64)
    const float* prof = (const float*)d_in[2];   // (16, 64)

    // ws: rec4 (4 MB) then recP (1 MB); total 5 MB.
    float4* rec4 = (float4*)d_ws;
    float*  recP = (float*)((char*)d_ws + (size_t)NB * 64 * 2 * NROWS2 * sizeof(float4));

    hm_recs<<<NB * 8, 256, 0, stream>>>(f0, harm, prof, rec4, recP);
    hm_synth<<<NB * 128, 64, 0, stream>>>(rec4, recP, (float*)d_out);
}

// Round 10
// 16.979 us; speedup vs baseline: 1.3947x; 1.3947x over previous
//
#include <hip/hip_runtime.h>
#include <hip/hip_fp16.h>
#include <math.h>

#define NVOICE 8
#define NPROF  16
#define NHARM  64
#define NFRAME 64
#define NSAMP  16384
#define NB     16

// Only harmonics h in [0,15] can ever have freq < 1.0.  For h >= 16,
// base*(h+1)^2 >= MIN_FREQ*289 = 1.048 > 1 for every frame, so freq clips
// to exactly 1.0, the phase prefix is an even integer, S is an integer,
// and sin(pi*S) == 0 exactly: those rows contribute nothing.
#define NKEEP  16
#define NROWS2 (NVOICE * NKEEP)        // 128 rows per batch

// MIN_FREQ = FREQ_INTERVAL = 40 / 11025
__device__ __forceinline__ float min_freq() { return 40.0f / 11025.0f; }

union U32H2 { unsigned u; __half2 h; };

// ---------------------------------------------------------------------------
// Fully fused kernel: one 256-thread block per (batch, quad of 256-sample
// chunks c0..c0+3).
//   step 1: base/amp0 for all (v,frame); prof -> LDS
//   step 2: per-row f64 phase prefix (4-frame-blocked tree to cut the
//           dependent chain ~3x; f32 per-frame terms IDENTICAL to before)
//           || softmax at the 6 touched frames (threads 128-175)
//   step 3: amplitudes at the 6 frames
//   step 4: packed records per (chunk,half,row): {A:f16, dA:f16, P2:f32}
//           = 8 B/row -> one b128 feeds TWO rows in the main loop.
// Main loop: wave = chunk q; lanes 0-31 half 0, lanes 32-63 half 1; each
// lane 4 samples.  F is recomputed in registers from 2 per-voice scalars:
//   F2 = min(base * ((h+1)^2/2), 0.5)   ((h+1)^2/2 = compile-time const)
//   S/2 = P2 + t1*F2 + t2*dF2,  t1=j+1, t2=(j+1)^2/512,  fa = A + t3*dA
//   sin(pi*S) = v_sin_f32(fract(S/2))   [v_sin takes revolutions]
// ---------------------------------------------------------------------------
__global__ __launch_bounds__(256)
void hm_fused(const float* __restrict__ f0,
              const float* __restrict__ harm,
              const float* __restrict__ prof,
              float* __restrict__ out)
{
    const int blk = blockIdx.x;          // 0..255
    const int b   = blk >> 4;
    const int qd  = blk & 15;            // chunk quad
    const int c0  = qd * 4;
    const int c3  = c0 + 3;
    const int tid = threadIdx.x;         // 0..255

    __shared__ float sBase[NVOICE][NFRAME];
    __shared__ float sAmp0[NVOICE][NFRAME];
    __shared__ float sProf[NPROF][NKEEP];
    __shared__ float sW[NVOICE][6][NPROF];     // softmax at the 6 frames
    __shared__ float sPP[5][NROWS2];           // P2 at frames c0-1 .. c0+3
    __shared__ float sA[6][NROWS2];            // amps at the 6 frames
    __shared__ uint4 pr[4][2][NROWS2 / 2];     // [q][half]: 2 rows/record

    // ---- step 1: prof; base & amp0 for all (v, k) -------------------------
    sProf[tid >> 4][tid & 15] = prof[(tid >> 4) * NHARM + (tid & 15)];
    if (c0 == 0 && tid < NROWS2) sPP[0][tid] = 0.0f;   // frame -1 prefix

    for (int idx = tid; idx < NVOICE * NFRAME; idx += 256) {
        const int v = idx >> 6, k = idx & 63;
        const float re  = f0[((size_t)b * 16 + 2 * v    ) * NFRAME + k];
        const float im  = f0[((size_t)b * 16 + 2 * v + 1) * NFRAME + k];
        const float ang = atan2f(im, re) * 0.3183098861837907f;   // /pi
        sBase[v][k] = min_freq() + ang * ang * min_freq();
        sAmp0[v][k] = re * re + im * im;
    }
    __syncthreads();

    // ---- step 2: phase prefix (threads 0-127) || softmax (128-175) --------
    if (tid < NROWS2) {
        // term_0 = 64*F_0; term_k = 64*(F_{k-1}+F_k); P2_k = frac(sum), f64.
        // Blocked by 4 frames: terms are the SAME f32 sums as the serial
        // version; only the (exact) f64 association changes -> ~3x shorter
        // dependent chain.  Checkpoint frames c0-1..c0+3 handled serially.
        const int r = tid, v = r >> 4, hh = r & 15;
        const float r2 = (float)((hh + 1) * (hh + 1));
        double p = 0.0;
        float prevF = 0.0f;
        int k = 0;
        const int kb = max(0, c0 - 1) & ~3;    // blocked region: frames < kb
        for (; k < kb; k += 4) {
            const float Fa = fminf(sBase[v][k    ] * r2, 1.0f);
            const float Fb = fminf(sBase[v][k + 1] * r2, 1.0f);
            const float Fc = fminf(sBase[v][k + 2] * r2, 1.0f);
            const float Fd = fminf(sBase[v][k + 3] * r2, 1.0f);
            const double t0 = (double)(prevF + Fa);
            const double t1 = (double)(Fa + Fb);
            const double t2 = (double)(Fb + Fc);
            const double t3 = (double)(Fc + Fd);
            p += 64.0 * ((t0 + t1) + (t2 + t3));
            prevF = Fd;
        }
        for (; k <= c3; ++k) {                 // <= 8 serial iterations
            const float F = fminf(sBase[v][k] * r2, 1.0f);
            p += 64.0 * (double)(prevF + F);
            prevF = F;
            const int fi = k - (c0 - 1);
            if (fi >= 0) sPP[fi][r] = (float)(p - floor(p));
        }
    } else if (tid < 128 + 48) {
        // 48 softmaxes: (v, fi) over the 6 frames c0-1 .. c0+4 (clamped)
        const int t = tid - 128;
        const int v = t / 6, fi = t % 6;
        const int f = min(max(c0 - 1 + fi, 0), 63);
        float w[NPROF];
        float m = -INFINITY;
#pragma unroll
        for (int p = 0; p < NPROF; ++p) {
            w[p] = harm[((size_t)b * (NVOICE * NPROF) + v * NPROF + p) * NFRAME + f];
            m = fmaxf(m, w[p]);
        }
        float s = 0.0f;
#pragma unroll
        for (int p = 0; p < NPROF; ++p) { w[p] = expf(w[p] - m); s += w[p]; }
        const float inv = 1.0f / s;
#pragma unroll
        for (int p = 0; p < NPROF; ++p) sW[v][fi][p] = w[p] * inv;
    }
    __syncthreads();

    // ---- step 3: amplitudes at the 6 frames (768 values) ------------------
    for (int idx = tid; idx < 6 * NROWS2; idx += 256) {
        const int fi = idx >> 7, r = idx & 127, v = r >> 4, hh = r & 15;
        const int f = min(max(c0 - 1 + fi, 0), 63);
        const float a0 = sAmp0[v][f];
        float A = a0;                            // hh==0: fundamental
        if (hh != 0) {
            float d = 0.0f;
#pragma unroll
            for (int p = 0; p < NPROF; ++p) d = fmaf(sW[v][fi][p], sProf[p][hh - 1], d);
            A = fminf(fmaxf(d, 0.0f), 1.0f) * a0;
        }
        sA[fi][r] = A;
    }
    __syncthreads();

    // ---- step 4: packed records: 8 (q,half) x 64 row-pairs ----------------
    for (int idx = tid; idx < 8 * (NROWS2 / 2); idx += 256) {
        const int qh = idx >> 6, g = idx & 63;       // row pair: rows 2g, 2g+1
        const int q = qh >> 1, hh2 = qh & 1;
        const int fiA = q + hh2, fiB = fiA + 1;
        const int r0 = 2 * g, r1 = 2 * g + 1;
        const float Aa0 = sA[fiA][r0], Ad0 = sA[fiB][r0] - Aa0;
        const float Aa1 = sA[fiA][r1], Ad1 = sA[fiB][r1] - Aa1;
        U32H2 u0; u0.h = __floats2half2_rn(Aa0, Ad0);
        U32H2 u1; u1.h = __floats2half2_rn(Aa1, Ad1);
        uint4 rec;
        rec.x = u0.u;
        rec.y = __float_as_uint(sPP[fiA][r0]);
        rec.z = u1.u;
        rec.w = __float_as_uint(sPP[fiA][r1]);
        pr[q][hh2][g] = rec;
    }
    __syncthreads();

    // ---- step 5: sample synthesis, S=4 per thread, register-F -------------
    const int q    = tid >> 6;           // chunk in quad (wave-uniform)
    const int lane = tid & 63;
    const int h    = lane >> 5;          // per-lane half (2-addr broadcast: free)
    const int l    = lane & 31;
    const int c    = c0 + q;

    float t1[4], t2[4], t3[4];
#pragma unroll
    for (int u = 0; u < 4; ++u) {
        const int j = l + 32 * u + (h ? 0 : 128);   // in-segment index
        float t1v = (float)(j + 1);
        if (c == 0 && h == 0) t1v = (float)(l + 32 * u + 1);  // flat head
        t1[u] = t1v;
        t2[u] = (float)((j + 1) * (j + 1)) * (1.0f / 512.0f);
        t3[u] = ((float)j + 0.5f) * (1.0f / 256.0f);
    }

    const int fA = min(max(c - 1 + h, 0), 63);
    const int fB = min(c + h, 63);
    const uint4* __restrict__ R = pr[q][h];

    float acc[4] = {0.0f, 0.0f, 0.0f, 0.0f};
#pragma unroll 2
    for (int v = 0; v < NVOICE; ++v) {
        const float bA = sBase[v][fA];
        const float bB = sBase[v][fB];
#pragma unroll
        for (int hp = 0; hp < 8; ++hp) {          // row pair (2hp, 2hp+1)
            const uint4 rec = R[v * 8 + hp];
            const float c2a = 0.5f * (float)((2 * hp + 1) * (2 * hp + 1));
            const float c2b = 0.5f * (float)((2 * hp + 2) * (2 * hp + 2));
            {   // row hh = 2hp
                const float F2a = fminf(bA * c2a, 0.5f);
                const float dF2 = fminf(bB * c2a, 0.5f) - F2a;
                U32H2 cv; cv.u = rec.x;
                const float A  = __low2float(cv.h);
                const float dA = __high2float(cv.h);
                const float P2 = __uint_as_float(rec.y);
#pragma unroll
                for (int u = 0; u < 4; ++u) {
                    const float x  = fmaf(t2[u], dF2, fmaf(t1[u], F2a, P2));
                    const float fa = fmaf(t3[u], dA, A);
                    acc[u] = fmaf(fa,
                        __builtin_amdgcn_sinf(__builtin_amdgcn_fractf(x)), acc[u]);
                }
            }
            {   // row hh = 2hp+1
                const float F2a = fminf(bA * c2b, 0.5f);
                const float dF2 = fminf(bB * c2b, 0.5f) - F2a;
                U32H2 cv; cv.u = rec.z;
                const float A  = __low2float(cv.h);
                const float dA = __high2float(cv.h);
                const float P2 = __uint_as_float(rec.w);
#pragma unroll
                for (int u = 0; u < 4; ++u) {
                    const float x  = fmaf(t2[u], dF2, fmaf(t1[u], F2a, P2));
                    const float fa = fmaf(t3[u], dA, A);
                    acc[u] = fmaf(fa,
                        __builtin_amdgcn_sinf(__builtin_amdgcn_fractf(x)), acc[u]);
                }
            }
        }
    }

    float* o = out + (size_t)b * NSAMP + c * 256 + (h ? 128 : 0) + l;
    o[0]  = acc[0];
    o[32] = acc[1];
    o[64] = acc[2];
    o[96] = acc[3];
}

// ---------------------------------------------------------------------------
extern "C" void kernel_launch(void* const* d_in, const int* in_sizes, int n_in,
                              void* d_out, int out_size, void* d_ws, size_t ws_size,
                              hipStream_t stream)
{
    const float* f0   = (const float*)d_in[0];   // (16, 16, 64)
    const float* harm = (const float*)d_in[1];   // (16, 128, 64)
    const float* prof = (const float*)d_in[2];   // (16, 64)

    hm_fused<<<NB * 16, 256, 0, stream>>>(f0, harm, prof, (float*)d_out);
}